// Round 11
// baseline (241.929 us; speedup 1.0000x reference)
//
#include <hip/hip_runtime.h>
#include <stdint.h>

typedef __bf16 bf16;
typedef __bf16 bf16x8 __attribute__((ext_vector_type(8)));
typedef __bf16 bf16x4 __attribute__((ext_vector_type(4)));
typedef float  f32x4  __attribute__((ext_vector_type(4)));

#define E_DIM 1024
#define S_LEN 2048
#define BATCH 2
#define NH 16
#define DH 64

#define NEG_INF (-__builtin_inff())

// async global->LDS, 16B per lane; LDS dst = wave-uniform base + lane*16 (m104)
__device__ __forceinline__ void load_lds16(const bf16* g, bf16* l) {
    __builtin_amdgcn_global_load_lds(
        (const __attribute__((address_space(1))) void*)g,
        (__attribute__((address_space(3))) void*)l, 16, 0, 0);
}

// ---------------------------------------------------------------------------
// fp32 -> bf16 conversion for x, Wq, Wk, Wv, Wo
// ---------------------------------------------------------------------------
__global__ __launch_bounds__(256) void convert_kernel(
    const float* __restrict__ s0, const float* __restrict__ s1,
    const float* __restrict__ s2, const float* __restrict__ s3,
    const float* __restrict__ s4,
    bf16* __restrict__ d0, bf16* __restrict__ d1, bf16* __restrict__ d2,
    bf16* __restrict__ d3, bf16* __restrict__ d4,
    int n0, int n1)
{
    const float* src; bf16* dst; int n;
    switch (blockIdx.y) {
        case 0:  src = s0; dst = d0; n = n0; break;
        case 1:  src = s1; dst = d1; n = n1; break;
        case 2:  src = s2; dst = d2; n = n1; break;
        case 3:  src = s3; dst = d3; n = n1; break;
        default: src = s4; dst = d4; n = n1; break;
    }
    int i = (blockIdx.x * 256 + threadIdx.x) * 4;
    if (i >= n) return;
    float4 v = *(const float4*)(src + i);
    bf16x4 o;
    o[0] = (bf16)v.x; o[1] = (bf16)v.y; o[2] = (bf16)v.z; o[3] = (bf16)v.w;
    *(bf16x4*)(dst + i) = o;
}

// ---------------------------------------------------------------------------
// GEMM, m97 staging + BK=64 (unchanged from R10): C = A * W^T + bias
// ---------------------------------------------------------------------------
__global__ __launch_bounds__(256) void gemm_kernel(
    const bf16* __restrict__ A,
    const bf16* __restrict__ W0, const bf16* __restrict__ W1, const bf16* __restrict__ W2,
    const float* __restrict__ bias0, const float* __restrict__ bias1, const float* __restrict__ bias2,
    bf16* __restrict__ outQ, bf16* __restrict__ outK, bf16* __restrict__ outVt,
    float* __restrict__ outF, int final_mode)
{
    __shared__ bf16 As0[128 * 32], As1[128 * 32];   // 8 KB each
    __shared__ bf16 Bs0[128 * 32], Bs1[128 * 32];

    int mode;
    const bf16* W; const float* bias;
    if (final_mode) { mode = 3; W = W0; bias = bias0; }
    else {
        mode = blockIdx.z;
        W    = (mode == 0) ? W0 : (mode == 1 ? W1 : W2);
        bias = (mode == 0) ? bias0 : (mode == 1 ? bias1 : bias2);
    }

    const int bm = blockIdx.y * 128, bn = blockIdx.x * 128;
    const int t = threadIdx.x;
    const int lane = t & 63, w = t >> 6;
    const int quad = lane >> 4, l16 = lane & 15;
    const int wm = (w & 1) * 64, wn = (w >> 1) * 64;

    const int r0 = w * 16;
    const int srow = r0 + (lane >> 2), scol = (lane & 3) * 8;
    const bf16* Ag0 = A + (size_t)(bm + srow) * E_DIM + scol;
    const bf16* Ag1 = Ag0 + (size_t)64 * E_DIM;
    const bf16* Wg0 = W + (size_t)(bn + srow) * E_DIM + scol;
    const bf16* Wg1 = Wg0 + (size_t)64 * E_DIM;
    bf16* a00 = As0 + r0 * 32;  bf16* a01 = As0 + (64 + r0) * 32;
    bf16* a10 = As1 + r0 * 32;  bf16* a11 = As1 + (64 + r0) * 32;
    bf16* b00 = Bs0 + r0 * 32;  bf16* b01 = Bs0 + (64 + r0) * 32;
    bf16* b10 = Bs1 + r0 * 32;  bf16* b11 = Bs1 + (64 + r0) * 32;

    f32x4 acc[4][4];
#pragma unroll
    for (int i = 0; i < 4; i++)
#pragma unroll
        for (int j = 0; j < 4; j++) acc[i][j] = f32x4{0.f, 0.f, 0.f, 0.f};

    for (int kt = 0; kt < E_DIM; kt += 64) {
        __syncthreads();
        load_lds16(Ag0 + kt,      a00);
        load_lds16(Ag1 + kt,      a01);
        load_lds16(Ag0 + kt + 32, a10);
        load_lds16(Ag1 + kt + 32, a11);
        load_lds16(Wg0 + kt,      b00);
        load_lds16(Wg1 + kt,      b01);
        load_lds16(Wg0 + kt + 32, b10);
        load_lds16(Wg1 + kt + 32, b11);
        __syncthreads();

#pragma unroll
        for (int half = 0; half < 2; half++) {
            const bf16* Asx = half ? As1 : As0;
            const bf16* Bsx = half ? Bs1 : Bs0;
            bf16x8 af[4], bfr[4];
#pragma unroll
            for (int i = 0; i < 4; i++)
                af[i] = *(const bf16x8*)(Asx + (wm + i * 16 + l16) * 32 + quad * 8);
#pragma unroll
            for (int j = 0; j < 4; j++)
                bfr[j] = *(const bf16x8*)(Bsx + (wn + j * 16 + l16) * 32 + quad * 8);
#pragma unroll
            for (int i = 0; i < 4; i++)
#pragma unroll
                for (int j = 0; j < 4; j++)
                    acc[i][j] = __builtin_amdgcn_mfma_f32_16x16x32_bf16(af[i], bfr[j], acc[i][j], 0, 0, 0);
        }
    }

#pragma unroll
    for (int j = 0; j < 4; j++) {
        const int n = bn + wn + j * 16 + l16;
        const float bv = bias[n];
#pragma unroll
        for (int i = 0; i < 4; i++) {
            const int m0 = bm + wm + i * 16 + quad * 4;
            if (mode == 3) {
#pragma unroll
                for (int r = 0; r < 4; r++)
                    outF[(size_t)(m0 + r) * E_DIM + n] = acc[i][j][r] + bv;
            } else if (mode == 2) {
                const int b_ = m0 >> 11, s0 = m0 & (S_LEN - 1);
                const int h = n >> 6, d = n & 63;
                bf16x4 pv;
#pragma unroll
                for (int r = 0; r < 4; r++) pv[r] = (bf16)(acc[i][j][r] + bv);
                *(bf16x4*)(outVt + ((size_t)((b_ * NH + h) * DH + d)) * S_LEN + s0) = pv;
            } else {
                bf16* o = (mode == 0) ? outQ : outK;
                const float sc = (mode == 0) ? 0.125f : 1.0f;
                const int h = n >> 6, d = n & 63;
#pragma unroll
                for (int r = 0; r < 4; r++) {
                    const int m = m0 + r;
                    const int b_ = m >> 11, s = m & (S_LEN - 1);
                    o[((size_t)(b_ * NH + h) * S_LEN + s) * DH + d] = (bf16)((acc[i][j][r] + bv) * sc);
                }
            }
        }
    }
}

// ---------------------------------------------------------------------------
// Flash attention, causal — 64-row q-tiles, balanced pairs, 2 blocks/CU.
// R10 post-mortem: halving LDS traffic didn't move time -> the limit is
// exposed LDS/VALU latency at 1 wave/SIMD (grid 256 = 1 block/CU). Here:
// 32 q-tiles of 64 rows; block owns pair (p, 31-p) -> (p/2+1)+((31-p)/2+1)
// = 17 k-tile-products, constant. Grid 512 = exactly 2 blocks/CU = 2
// waves/SIMD, doubling stall coverage at uniform balance. Each wave owns a
// 16-row stripe of each q-tile; q_lo and q_hi processed sequentially per
// staged tile, reusing one 16-row P buffer (LDS 52 KB -> two blocks fit).
// Plain launch_bounds(256): VGPRs float (<256 keeps 2 waves/SIMD; no forced
// cap -> no R5-style spill). Unnormalized softmax as R7-R10.
// ---------------------------------------------------------------------------
__global__ __launch_bounds__(256) void attn_kernel(
    const bf16* __restrict__ Qb, const bf16* __restrict__ Kb,
    const bf16* __restrict__ Vtb, bf16* __restrict__ Ob)
{
    __shared__ bf16 Ks[128 * 72];      // [kk][d]   18.0 KB
    __shared__ bf16 Vs[64 * 136];      // [d][kk]   17.0 KB
    __shared__ bf16 Ps[4][16 * 136];   // per-wave P stripe  17.0 KB

    const int t = threadIdx.x, lane = t & 63, w = t >> 6;
    const int quad = lane >> 4, l16 = lane & 15;

    // 512 blocks: XCD gets 4 bh values (2 MB K/V -> L2-resident)
    const int i = blockIdx.x;
    const int xcd = i & 7, rr = i >> 3;        // rr: 0..63
    const int bh = (xcd << 2) | (rr & 3);
    const int pr = rr >> 2;                    // pair index 0..15
    const int qtl = pr, qth = 31 - pr;         // the two 64-row q-tiles

    const bf16* Qg = Qb + (size_t)bh * S_LEN * DH;
    const bf16* Kg = Kb + (size_t)bh * S_LEN * DH;
    const bf16* Vg = Vtb + (size_t)bh * DH * S_LEN;
    const int b_ = bh >> 4, h = bh & 15;
    bf16* Og = Ob + (size_t)b_ * S_LEN * E_DIM + h * DH;

    bf16* Pw = Ps[w];

    // Q A-fragments: one 16-row stripe per q-tile per wave
    bf16x8 aq[2][2];
#pragma unroll
    for (int qt = 0; qt < 2; qt++) {
        const int qrow0 = (qt ? qth : qtl) * 64 + w * 16;
        const bf16* qp = Qg + (size_t)(qrow0 + l16) * DH + quad * 8;
        aq[qt][0] = *(const bf16x8*)(qp);
        aq[qt][1] = *(const bf16x8*)(qp + 32);
    }

    f32x4 o[2][4];
    float l_part[2][4];
#pragma unroll
    for (int qt = 0; qt < 2; qt++)
#pragma unroll
        for (int dt = 0; dt < 4; dt++) {
            o[qt][dt] = f32x4{0.f, 0.f, 0.f, 0.f};
            l_part[qt][dt] = 0.f;
        }

    const int nkt_lo = (qtl >> 1) + 1;
    const int T = (qth >> 1) + 1;              // staged k-tiles: 9..16
    const int krow = t >> 3, kcol8 = (t & 7) * 8;
    const int vrow = t >> 4, vcol8 = (t & 15) * 8;

    // prefetch tile 0 into registers
    uint4 kc[4], vc[4];
#pragma unroll
    for (int k = 0; k < 4; k++)
        kc[k] = *(const uint4*)(Kg + (size_t)(krow + 32 * k) * DH + kcol8);
#pragma unroll
    for (int k = 0; k < 4; k++)
        vc[k] = *(const uint4*)(Vg + (size_t)(vrow + 16 * k) * S_LEN + vcol8);

    for (int kt = 0; kt < T; kt++) {
        __syncthreads();   // previous tile's LDS reads done
#pragma unroll
        for (int k = 0; k < 4; k++)
            *(uint4*)(Ks + (krow + 32 * k) * 72 + kcol8) = kc[k];
#pragma unroll
        for (int k = 0; k < 4; k++)
            *(uint4*)(Vs + (vrow + 16 * k) * 136 + vcol8) = vc[k];
        __syncthreads();   // staged tile visible

        // prefetch NEXT tile (lands during compute below)
        if (kt + 1 < T) {
            const int nb = (kt + 1) * 128;
#pragma unroll
            for (int k = 0; k < 4; k++)
                kc[k] = *(const uint4*)(Kg + (size_t)(nb + krow + 32 * k) * DH + kcol8);
#pragma unroll
            for (int k = 0; k < 4; k++)
                vc[k] = *(const uint4*)(Vg + (size_t)(vrow + 16 * k) * S_LEN + nb + vcol8);
        }

#pragma unroll
        for (int qt = 0; qt < 2; qt++) {
            if (qt == 0 && kt >= nkt_lo) continue;     // q_lo only needs its tiles
            const int qtile = qt ? qth : qtl;
            const bool diag = (kt == (qtile >> 1));

            // S = Q K^T for this 16-row stripe (K frags from LDS)
            f32x4 sv[8];
#pragma unroll
            for (int jt = 0; jt < 8; jt++) {
                const bf16* kp = Ks + (jt * 16 + l16) * 72 + quad * 8;
                bf16x8 bk0 = *(const bf16x8*)(kp);
                bf16x8 bk1 = *(const bf16x8*)(kp + 32);
                f32x4 s = f32x4{0.f, 0.f, 0.f, 0.f};
                s = __builtin_amdgcn_mfma_f32_16x16x32_bf16(aq[qt][0], bk0, s, 0, 0, 0);
                s = __builtin_amdgcn_mfma_f32_16x16x32_bf16(aq[qt][1], bk1, s, 0, 0, 0);
                sv[jt] = s;
            }

            if (diag) {
                // tile-relative: qrow_rel = 64*(qtile&1) + w*16 + quad*4 + r
                const int inrow_base = 64 * (qtile & 1) + w * 16 + quad * 4;
#pragma unroll
                for (int jt = 0; jt < 8; jt++) {
                    const int kcol = jt * 16 + l16;
#pragma unroll
                    for (int r = 0; r < 4; r++)
                        if (kcol > inrow_base + r) sv[jt][r] = NEG_INF;
                }
            }

            // p = exp(s), unnormalized; in-lane partial row sums
#pragma unroll
            for (int jt = 0; jt < 8; jt++)
#pragma unroll
                for (int r = 0; r < 4; r++) {
                    const float pe = __expf(sv[jt][r]);
                    sv[jt][r] = pe;
                    l_part[qt][r] += pe;
                }

            // P: C-layout -> LDS -> A-layout (per-wave private; no barrier)
#pragma unroll
            for (int jt = 0; jt < 8; jt++)
#pragma unroll
                for (int r = 0; r < 4; r++)
                    Pw[(quad * 4 + r) * 136 + jt * 16 + l16] = (bf16)sv[jt][r];

            // O += P V (V frags from LDS)
#pragma unroll
            for (int ks = 0; ks < 4; ks++) {
                bf16x8 ap = *(const bf16x8*)(Pw + l16 * 136 + ks * 32 + quad * 8);
#pragma unroll
                for (int dt = 0; dt < 4; dt++) {
                    bf16x8 bv = *(const bf16x8*)(Vs + (dt * 16 + l16) * 136 + ks * 32 + quad * 8);
                    o[qt][dt] = __builtin_amdgcn_mfma_f32_16x16x32_bf16(ap, bv, o[qt][dt], 0, 0, 0);
                }
            }
        }
    }

    // epilogue: reduce row sums, normalize, write both q-tiles
#pragma unroll
    for (int qt = 0; qt < 2; qt++) {
        const int qrow0 = (qt ? qth : qtl) * 64 + w * 16;
#pragma unroll
        for (int r = 0; r < 4; r++) {
            float l = l_part[qt][r];
            l += __shfl_xor(l, 1);
            l += __shfl_xor(l, 2);
            l += __shfl_xor(l, 4);
            l += __shfl_xor(l, 8);
            l_part[qt][r] = 1.0f / l;
        }
#pragma unroll
        for (int r = 0; r < 4; r++) {
            const int srow = qrow0 + quad * 4 + r;
#pragma unroll
            for (int dt = 0; dt < 4; dt++)
                Og[(size_t)srow * E_DIM + dt * 16 + l16] =
                    (bf16)(o[qt][dt][r] * l_part[qt][r]);
        }
    }
}

// ---------------------------------------------------------------------------
extern "C" void kernel_launch(void* const* d_in, const int* in_sizes, int n_in,
                              void* d_out, int out_size, void* d_ws, size_t ws_size,
                              hipStream_t stream)
{
    const float* x  = (const float*)d_in[0];
    const float* Wq = (const float*)d_in[1];
    const float* bq = (const float*)d_in[2];
    const float* Wk = (const float*)d_in[3];
    const float* bk = (const float*)d_in[4];
    const float* Wv = (const float*)d_in[5];
    const float* bv = (const float*)d_in[6];
    const float* Wo = (const float*)d_in[7];
    const float* bo = (const float*)d_in[8];
    float* out = (float*)d_out;

    char* ws = (char*)d_ws;
    const size_t MB = 1ull << 20;
    bf16* xb  = (bf16*)(ws + 0);        //  8 MB: x   bf16 [4096][1024]
    bf16* wqb = (bf16*)(ws + 8 * MB);   //  2 MB
    bf16* wkb = (bf16*)(ws + 10 * MB);  //  2 MB
    bf16* wvb = (bf16*)(ws + 12 * MB);  //  2 MB
    bf16* wob = (bf16*)(ws + 14 * MB);  //  2 MB
    bf16* Qb  = (bf16*)(ws + 16 * MB);  //  8 MB: [b][h][s][d] (q pre-scaled by 1/8)
    bf16* Kb  = (bf16*)(ws + 24 * MB);  //  8 MB: [b][h][s][d]
    bf16* Vtb = (bf16*)(ws + 32 * MB);  //  8 MB: [b][h][d][s]
    bf16* Ab  = (bf16*)(ws + 40 * MB);  //  8 MB: attn out [b][s][e]

    // 1) fp32 -> bf16 for x and the four weight matrices
    convert_kernel<<<dim3(4096, 5), 256, 0, stream>>>(
        x, Wq, Wk, Wv, Wo, xb, wqb, wkb, wvb, wob, 4194304, 1048576);

    // 2) Q/K/V projections (z selects which), BK=64
    gemm_kernel<<<dim3(8, 32, 3), 256, 0, stream>>>(
        xb, wqb, wkb, wvb, bq, bk, bv, Qb, Kb, Vtb, nullptr, 0);

    // 3) causal flash attention (64-row q-tiles, balanced pairs, 2 blocks/CU)
    attn_kernel<<<dim3(512), 256, 0, stream>>>(Qb, Kb, Vtb, Ab);

    // 4) output projection -> fp32 d_out, BK=64
    gemm_kernel<<<dim3(8, 32, 1), 256, 0, stream>>>(
        Ab, wob, wob, wob, bo, bo, bo, nullptr, nullptr, nullptr, out, 1);
}

// Round 12
// 239.885 us; speedup vs baseline: 1.0085x; 1.0085x over previous
//
#include <hip/hip_runtime.h>
#include <stdint.h>

typedef __bf16 bf16;
typedef __bf16 bf16x8 __attribute__((ext_vector_type(8)));
typedef __bf16 bf16x4 __attribute__((ext_vector_type(4)));
typedef float  f32x4  __attribute__((ext_vector_type(4)));

#define E_DIM 1024
#define S_LEN 2048
#define BATCH 2
#define NH 16
#define DH 64

#define NEG_INF (-__builtin_inff())

// async global->LDS, 16B per lane; LDS dst = wave-uniform base + lane*16 (m104)
__device__ __forceinline__ void load_lds16(const bf16* g, bf16* l) {
    __builtin_amdgcn_global_load_lds(
        (const __attribute__((address_space(1))) void*)g,
        (__attribute__((address_space(3))) void*)l, 16, 0, 0);
}

// ---------------------------------------------------------------------------
// fp32 -> bf16 conversion for x, Wq, Wk, Wv, Wo
// ---------------------------------------------------------------------------
__global__ __launch_bounds__(256) void convert_kernel(
    const float* __restrict__ s0, const float* __restrict__ s1,
    const float* __restrict__ s2, const float* __restrict__ s3,
    const float* __restrict__ s4,
    bf16* __restrict__ d0, bf16* __restrict__ d1, bf16* __restrict__ d2,
    bf16* __restrict__ d3, bf16* __restrict__ d4,
    int n0, int n1)
{
    const float* src; bf16* dst; int n;
    switch (blockIdx.y) {
        case 0:  src = s0; dst = d0; n = n0; break;
        case 1:  src = s1; dst = d1; n = n1; break;
        case 2:  src = s2; dst = d2; n = n1; break;
        case 3:  src = s3; dst = d3; n = n1; break;
        default: src = s4; dst = d4; n = n1; break;
    }
    int i = (blockIdx.x * 256 + threadIdx.x) * 4;
    if (i >= n) return;
    float4 v = *(const float4*)(src + i);
    bf16x4 o;
    o[0] = (bf16)v.x; o[1] = (bf16)v.y; o[2] = (bf16)v.z; o[3] = (bf16)v.w;
    *(bf16x4*)(dst + i) = o;
}

// ---------------------------------------------------------------------------
// GEMM, m97 staging + BK=64 (unchanged from R10/R11): C = A * W^T + bias
// ---------------------------------------------------------------------------
__global__ __launch_bounds__(256) void gemm_kernel(
    const bf16* __restrict__ A,
    const bf16* __restrict__ W0, const bf16* __restrict__ W1, const bf16* __restrict__ W2,
    const float* __restrict__ bias0, const float* __restrict__ bias1, const float* __restrict__ bias2,
    bf16* __restrict__ outQ, bf16* __restrict__ outK, bf16* __restrict__ outVt,
    float* __restrict__ outF, int final_mode)
{
    __shared__ bf16 As0[128 * 32], As1[128 * 32];   // 8 KB each
    __shared__ bf16 Bs0[128 * 32], Bs1[128 * 32];

    int mode;
    const bf16* W; const float* bias;
    if (final_mode) { mode = 3; W = W0; bias = bias0; }
    else {
        mode = blockIdx.z;
        W    = (mode == 0) ? W0 : (mode == 1 ? W1 : W2);
        bias = (mode == 0) ? bias0 : (mode == 1 ? bias1 : bias2);
    }

    const int bm = blockIdx.y * 128, bn = blockIdx.x * 128;
    const int t = threadIdx.x;
    const int lane = t & 63, w = t >> 6;
    const int quad = lane >> 4, l16 = lane & 15;
    const int wm = (w & 1) * 64, wn = (w >> 1) * 64;

    const int r0 = w * 16;
    const int srow = r0 + (lane >> 2), scol = (lane & 3) * 8;
    const bf16* Ag0 = A + (size_t)(bm + srow) * E_DIM + scol;
    const bf16* Ag1 = Ag0 + (size_t)64 * E_DIM;
    const bf16* Wg0 = W + (size_t)(bn + srow) * E_DIM + scol;
    const bf16* Wg1 = Wg0 + (size_t)64 * E_DIM;
    bf16* a00 = As0 + r0 * 32;  bf16* a01 = As0 + (64 + r0) * 32;
    bf16* a10 = As1 + r0 * 32;  bf16* a11 = As1 + (64 + r0) * 32;
    bf16* b00 = Bs0 + r0 * 32;  bf16* b01 = Bs0 + (64 + r0) * 32;
    bf16* b10 = Bs1 + r0 * 32;  bf16* b11 = Bs1 + (64 + r0) * 32;

    f32x4 acc[4][4];
#pragma unroll
    for (int i = 0; i < 4; i++)
#pragma unroll
        for (int j = 0; j < 4; j++) acc[i][j] = f32x4{0.f, 0.f, 0.f, 0.f};

    for (int kt = 0; kt < E_DIM; kt += 64) {
        __syncthreads();
        load_lds16(Ag0 + kt,      a00);
        load_lds16(Ag1 + kt,      a01);
        load_lds16(Ag0 + kt + 32, a10);
        load_lds16(Ag1 + kt + 32, a11);
        load_lds16(Wg0 + kt,      b00);
        load_lds16(Wg1 + kt,      b01);
        load_lds16(Wg0 + kt + 32, b10);
        load_lds16(Wg1 + kt + 32, b11);
        __syncthreads();

#pragma unroll
        for (int half = 0; half < 2; half++) {
            const bf16* Asx = half ? As1 : As0;
            const bf16* Bsx = half ? Bs1 : Bs0;
            bf16x8 af[4], bfr[4];
#pragma unroll
            for (int i = 0; i < 4; i++)
                af[i] = *(const bf16x8*)(Asx + (wm + i * 16 + l16) * 32 + quad * 8);
#pragma unroll
            for (int j = 0; j < 4; j++)
                bfr[j] = *(const bf16x8*)(Bsx + (wn + j * 16 + l16) * 32 + quad * 8);
#pragma unroll
            for (int i = 0; i < 4; i++)
#pragma unroll
                for (int j = 0; j < 4; j++)
                    acc[i][j] = __builtin_amdgcn_mfma_f32_16x16x32_bf16(af[i], bfr[j], acc[i][j], 0, 0, 0);
        }
    }

#pragma unroll
    for (int j = 0; j < 4; j++) {
        const int n = bn + wn + j * 16 + l16;
        const float bv = bias[n];
#pragma unroll
        for (int i = 0; i < 4; i++) {
            const int m0 = bm + wm + i * 16 + quad * 4;
            if (mode == 3) {
#pragma unroll
                for (int r = 0; r < 4; r++)
                    outF[(size_t)(m0 + r) * E_DIM + n] = acc[i][j][r] + bv;
            } else if (mode == 2) {
                const int b_ = m0 >> 11, s0 = m0 & (S_LEN - 1);
                const int h = n >> 6, d = n & 63;
                bf16x4 pv;
#pragma unroll
                for (int r = 0; r < 4; r++) pv[r] = (bf16)(acc[i][j][r] + bv);
                *(bf16x4*)(outVt + ((size_t)((b_ * NH + h) * DH + d)) * S_LEN + s0) = pv;
            } else {
                bf16* o = (mode == 0) ? outQ : outK;
                const float sc = (mode == 0) ? 0.125f : 1.0f;
                const int h = n >> 6, d = n & 63;
#pragma unroll
                for (int r = 0; r < 4; r++) {
                    const int m = m0 + r;
                    const int b_ = m >> 11, s = m & (S_LEN - 1);
                    o[((size_t)(b_ * NH + h) * S_LEN + s) * DH + d] = (bf16)((acc[i][j][r] + bv) * sc);
                }
            }
        }
    }
}

// ---------------------------------------------------------------------------
// Flash attention, causal — R11 structure (64-row q-tiles, balanced pairs,
// 512 blocks = 2 blocks/CU) with the register budget DECLARED:
// __launch_bounds__(256, 2) -> 2 waves/SIMD -> 256 VGPRs/wave available
// (m69: waves/SIMD halve at vgpr={64,128,256}). R11's default bounds made
// the compiler target 4 waves/SIMD (128-reg cap incl. AGPRs) and spill the
// prefetch arrays to scratch (WRITE_SIZE 130 MB, 1.5 TB/s) — which consumed
// the TLP gain. ~160 regs needed fits 256 with headroom; no spill.
// ---------------------------------------------------------------------------
__global__ __launch_bounds__(256, 2) void attn_kernel(
    const bf16* __restrict__ Qb, const bf16* __restrict__ Kb,
    const bf16* __restrict__ Vtb, bf16* __restrict__ Ob)
{
    __shared__ bf16 Ks[128 * 72];      // [kk][d]   18.0 KB
    __shared__ bf16 Vs[64 * 136];      // [d][kk]   17.0 KB
    __shared__ bf16 Ps[4][16 * 136];   // per-wave P stripe  17.0 KB

    const int t = threadIdx.x, lane = t & 63, w = t >> 6;
    const int quad = lane >> 4, l16 = lane & 15;

    // 512 blocks: XCD gets 4 bh values (2 MB K/V -> L2-resident)
    const int i = blockIdx.x;
    const int xcd = i & 7, rr = i >> 3;        // rr: 0..63
    const int bh = (xcd << 2) | (rr & 3);
    const int pr = rr >> 2;                    // pair index 0..15
    const int qtl = pr, qth = 31 - pr;         // the two 64-row q-tiles

    const bf16* Qg = Qb + (size_t)bh * S_LEN * DH;
    const bf16* Kg = Kb + (size_t)bh * S_LEN * DH;
    const bf16* Vg = Vtb + (size_t)bh * DH * S_LEN;
    const int b_ = bh >> 4, h = bh & 15;
    bf16* Og = Ob + (size_t)b_ * S_LEN * E_DIM + h * DH;

    bf16* Pw = Ps[w];

    // Q A-fragments: one 16-row stripe per q-tile per wave
    bf16x8 aq[2][2];
#pragma unroll
    for (int qt = 0; qt < 2; qt++) {
        const int qrow0 = (qt ? qth : qtl) * 64 + w * 16;
        const bf16* qp = Qg + (size_t)(qrow0 + l16) * DH + quad * 8;
        aq[qt][0] = *(const bf16x8*)(qp);
        aq[qt][1] = *(const bf16x8*)(qp + 32);
    }

    f32x4 o[2][4];
    float l_part[2][4];
#pragma unroll
    for (int qt = 0; qt < 2; qt++)
#pragma unroll
        for (int dt = 0; dt < 4; dt++) {
            o[qt][dt] = f32x4{0.f, 0.f, 0.f, 0.f};
            l_part[qt][dt] = 0.f;
        }

    const int nkt_lo = (qtl >> 1) + 1;
    const int T = (qth >> 1) + 1;              // staged k-tiles: 9..16
    const int krow = t >> 3, kcol8 = (t & 7) * 8;
    const int vrow = t >> 4, vcol8 = (t & 15) * 8;

    // prefetch tile 0 into registers
    uint4 kc[4], vc[4];
#pragma unroll
    for (int k = 0; k < 4; k++)
        kc[k] = *(const uint4*)(Kg + (size_t)(krow + 32 * k) * DH + kcol8);
#pragma unroll
    for (int k = 0; k < 4; k++)
        vc[k] = *(const uint4*)(Vg + (size_t)(vrow + 16 * k) * S_LEN + vcol8);

    for (int kt = 0; kt < T; kt++) {
        __syncthreads();   // previous tile's LDS reads done
#pragma unroll
        for (int k = 0; k < 4; k++)
            *(uint4*)(Ks + (krow + 32 * k) * 72 + kcol8) = kc[k];
#pragma unroll
        for (int k = 0; k < 4; k++)
            *(uint4*)(Vs + (vrow + 16 * k) * 136 + vcol8) = vc[k];
        __syncthreads();   // staged tile visible

        // prefetch NEXT tile (lands during compute below)
        if (kt + 1 < T) {
            const int nb = (kt + 1) * 128;
#pragma unroll
            for (int k = 0; k < 4; k++)
                kc[k] = *(const uint4*)(Kg + (size_t)(nb + krow + 32 * k) * DH + kcol8);
#pragma unroll
            for (int k = 0; k < 4; k++)
                vc[k] = *(const uint4*)(Vg + (size_t)(vrow + 16 * k) * S_LEN + nb + vcol8);
        }

#pragma unroll
        for (int qt = 0; qt < 2; qt++) {
            if (qt == 0 && kt >= nkt_lo) continue;     // q_lo only needs its tiles
            const int qtile = qt ? qth : qtl;
            const bool diag = (kt == (qtile >> 1));

            // S = Q K^T for this 16-row stripe (K frags from LDS)
            f32x4 sv[8];
#pragma unroll
            for (int jt = 0; jt < 8; jt++) {
                const bf16* kp = Ks + (jt * 16 + l16) * 72 + quad * 8;
                bf16x8 bk0 = *(const bf16x8*)(kp);
                bf16x8 bk1 = *(const bf16x8*)(kp + 32);
                f32x4 s = f32x4{0.f, 0.f, 0.f, 0.f};
                s = __builtin_amdgcn_mfma_f32_16x16x32_bf16(aq[qt][0], bk0, s, 0, 0, 0);
                s = __builtin_amdgcn_mfma_f32_16x16x32_bf16(aq[qt][1], bk1, s, 0, 0, 0);
                sv[jt] = s;
            }

            if (diag) {
                // tile-relative: qrow_rel = 64*(qtile&1) + w*16 + quad*4 + r
                const int inrow_base = 64 * (qtile & 1) + w * 16 + quad * 4;
#pragma unroll
                for (int jt = 0; jt < 8; jt++) {
                    const int kcol = jt * 16 + l16;
#pragma unroll
                    for (int r = 0; r < 4; r++)
                        if (kcol > inrow_base + r) sv[jt][r] = NEG_INF;
                }
            }

            // p = exp(s), unnormalized; in-lane partial row sums
#pragma unroll
            for (int jt = 0; jt < 8; jt++)
#pragma unroll
                for (int r = 0; r < 4; r++) {
                    const float pe = __expf(sv[jt][r]);
                    sv[jt][r] = pe;
                    l_part[qt][r] += pe;
                }

            // P: C-layout -> LDS -> A-layout (per-wave private; no barrier)
#pragma unroll
            for (int jt = 0; jt < 8; jt++)
#pragma unroll
                for (int r = 0; r < 4; r++)
                    Pw[(quad * 4 + r) * 136 + jt * 16 + l16] = (bf16)sv[jt][r];

            // O += P V (V frags from LDS)
#pragma unroll
            for (int ks = 0; ks < 4; ks++) {
                bf16x8 ap = *(const bf16x8*)(Pw + l16 * 136 + ks * 32 + quad * 8);
#pragma unroll
                for (int dt = 0; dt < 4; dt++) {
                    bf16x8 bv = *(const bf16x8*)(Vs + (dt * 16 + l16) * 136 + ks * 32 + quad * 8);
                    o[qt][dt] = __builtin_amdgcn_mfma_f32_16x16x32_bf16(ap, bv, o[qt][dt], 0, 0, 0);
                }
            }
        }
    }

    // epilogue: reduce row sums, normalize, write both q-tiles
#pragma unroll
    for (int qt = 0; qt < 2; qt++) {
        const int qrow0 = (qt ? qth : qtl) * 64 + w * 16;
#pragma unroll
        for (int r = 0; r < 4; r++) {
            float l = l_part[qt][r];
            l += __shfl_xor(l, 1);
            l += __shfl_xor(l, 2);
            l += __shfl_xor(l, 4);
            l += __shfl_xor(l, 8);
            l_part[qt][r] = 1.0f / l;
        }
#pragma unroll
        for (int r = 0; r < 4; r++) {
            const int srow = qrow0 + quad * 4 + r;
#pragma unroll
            for (int dt = 0; dt < 4; dt++)
                Og[(size_t)srow * E_DIM + dt * 16 + l16] =
                    (bf16)(o[qt][dt][r] * l_part[qt][r]);
        }
    }
}

// ---------------------------------------------------------------------------
extern "C" void kernel_launch(void* const* d_in, const int* in_sizes, int n_in,
                              void* d_out, int out_size, void* d_ws, size_t ws_size,
                              hipStream_t stream)
{
    const float* x  = (const float*)d_in[0];
    const float* Wq = (const float*)d_in[1];
    const float* bq = (const float*)d_in[2];
    const float* Wk = (const float*)d_in[3];
    const float* bk = (const float*)d_in[4];
    const float* Wv = (const float*)d_in[5];
    const float* bv = (const float*)d_in[6];
    const float* Wo = (const float*)d_in[7];
    const float* bo = (const float*)d_in[8];
    float* out = (float*)d_out;

    char* ws = (char*)d_ws;
    const size_t MB = 1ull << 20;
    bf16* xb  = (bf16*)(ws + 0);        //  8 MB: x   bf16 [4096][1024]
    bf16* wqb = (bf16*)(ws + 8 * MB);   //  2 MB
    bf16* wkb = (bf16*)(ws + 10 * MB);  //  2 MB
    bf16* wvb = (bf16*)(ws + 12 * MB);  //  2 MB
    bf16* wob = (bf16*)(ws + 14 * MB);  //  2 MB
    bf16* Qb  = (bf16*)(ws + 16 * MB);  //  8 MB: [b][h][s][d] (q pre-scaled by 1/8)
    bf16* Kb  = (bf16*)(ws + 24 * MB);  //  8 MB: [b][h][s][d]
    bf16* Vtb = (bf16*)(ws + 32 * MB);  //  8 MB: [b][h][d][s]
    bf16* Ab  = (bf16*)(ws + 40 * MB);  //  8 MB: attn out [b][s][e]

    // 1) fp32 -> bf16 for x and the four weight matrices
    convert_kernel<<<dim3(4096, 5), 256, 0, stream>>>(
        x, Wq, Wk, Wv, Wo, xb, wqb, wkb, wvb, wob, 4194304, 1048576);

    // 2) Q/K/V projections (z selects which), BK=64
    gemm_kernel<<<dim3(8, 32, 3), 256, 0, stream>>>(
        xb, wqb, wkb, wvb, bq, bk, bv, Qb, Kb, Vtb, nullptr, 0);

    // 3) causal flash attention (64-row q-tiles, balanced pairs, 2 blocks/CU,
    //    launch_bounds(256,2) -> 256-reg budget, no spill)
    attn_kernel<<<dim3(512), 256, 0, stream>>>(Qb, Kb, Vtb, Ab);

    // 4) output projection -> fp32 d_out, BK=64
    gemm_kernel<<<dim3(8, 32, 1), 256, 0, stream>>>(
        Ab, wob, wob, wob, bo, bo, bo, nullptr, nullptr, nullptr, out, 1);
}

// Round 13
// 232.168 us; speedup vs baseline: 1.0420x; 1.0332x over previous
//
#include <hip/hip_runtime.h>
#include <stdint.h>

typedef __bf16 bf16;
typedef __bf16 bf16x8 __attribute__((ext_vector_type(8)));
typedef __bf16 bf16x4 __attribute__((ext_vector_type(4)));
typedef float  f32x4  __attribute__((ext_vector_type(4)));

#define E_DIM 1024
#define S_LEN 2048
#define BATCH 2
#define NH 16
#define DH 64

#define NEG_INF (-__builtin_inff())

// async global->LDS, 16B per lane; LDS dst = wave-uniform base + lane*16 (m104)
__device__ __forceinline__ void load_lds16(const bf16* g, bf16* l) {
    __builtin_amdgcn_global_load_lds(
        (const __attribute__((address_space(1))) void*)g,
        (__attribute__((address_space(3))) void*)l, 16, 0, 0);
}

// ---------------------------------------------------------------------------
// fp32 -> bf16 conversion for x, Wq, Wk, Wv, Wo
// ---------------------------------------------------------------------------
__global__ __launch_bounds__(256) void convert_kernel(
    const float* __restrict__ s0, const float* __restrict__ s1,
    const float* __restrict__ s2, const float* __restrict__ s3,
    const float* __restrict__ s4,
    bf16* __restrict__ d0, bf16* __restrict__ d1, bf16* __restrict__ d2,
    bf16* __restrict__ d3, bf16* __restrict__ d4,
    int n0, int n1)
{
    const float* src; bf16* dst; int n;
    switch (blockIdx.y) {
        case 0:  src = s0; dst = d0; n = n0; break;
        case 1:  src = s1; dst = d1; n = n1; break;
        case 2:  src = s2; dst = d2; n = n1; break;
        case 3:  src = s3; dst = d3; n = n1; break;
        default: src = s4; dst = d4; n = n1; break;
    }
    int i = (blockIdx.x * 256 + threadIdx.x) * 4;
    if (i >= n) return;
    float4 v = *(const float4*)(src + i);
    bf16x4 o;
    o[0] = (bf16)v.x; o[1] = (bf16)v.y; o[2] = (bf16)v.z; o[3] = (bf16)v.w;
    *(bf16x4*)(dst + i) = o;
}

// ---------------------------------------------------------------------------
// GEMM: C = A * W^T + bias. m97 width-16 async staging + SINGLE-BARRIER
// double buffer: loads for tile k+1 are issued immediately after the barrier
// that publishes tile k, so the next barrier's vmcnt(0) drain finds them
// already landed (a full 16-MFMA compute section in flight). One barrier per
// k-step instead of two. BK=32 (beat BK=64 by ~6 us in R9/R10 A/B).
// ---------------------------------------------------------------------------
__global__ __launch_bounds__(256) void gemm_kernel(
    const bf16* __restrict__ A,
    const bf16* __restrict__ W0, const bf16* __restrict__ W1, const bf16* __restrict__ W2,
    const float* __restrict__ bias0, const float* __restrict__ bias1, const float* __restrict__ bias2,
    bf16* __restrict__ outQ, bf16* __restrict__ outK, bf16* __restrict__ outVt,
    float* __restrict__ outF, int final_mode)
{
    __shared__ bf16 As[2][128 * 32];   // 8 KB each
    __shared__ bf16 Bs[2][128 * 32];

    int mode;
    const bf16* W; const float* bias;
    if (final_mode) { mode = 3; W = W0; bias = bias0; }
    else {
        mode = blockIdx.z;
        W    = (mode == 0) ? W0 : (mode == 1 ? W1 : W2);
        bias = (mode == 0) ? bias0 : (mode == 1 ? bias1 : bias2);
    }

    const int bm = blockIdx.y * 128, bn = blockIdx.x * 128;
    const int t = threadIdx.x;
    const int lane = t & 63, w = t >> 6;
    const int quad = lane >> 4, l16 = lane & 15;
    const int wm = (w & 1) * 64, wn = (w >> 1) * 64;

    // staging map: wave w covers rows [w*16, w*16+16) and [64+w*16, ...)
    const int r0 = w * 16;
    const int srow = r0 + (lane >> 2), scol = (lane & 3) * 8;
    const bf16* Ag0 = A + (size_t)(bm + srow) * E_DIM + scol;
    const bf16* Ag1 = Ag0 + (size_t)64 * E_DIM;
    const bf16* Wg0 = W + (size_t)(bn + srow) * E_DIM + scol;
    const bf16* Wg1 = Wg0 + (size_t)64 * E_DIM;

    f32x4 acc[4][4];
#pragma unroll
    for (int i = 0; i < 4; i++)
#pragma unroll
        for (int j = 0; j < 4; j++) acc[i][j] = f32x4{0.f, 0.f, 0.f, 0.f};

    // issue tile 0 into buffer 0
    load_lds16(Ag0, As[0] + r0 * 32);
    load_lds16(Ag1, As[0] + (64 + r0) * 32);
    load_lds16(Wg0, Bs[0] + r0 * 32);
    load_lds16(Wg1, Bs[0] + (64 + r0) * 32);

    int cur = 0;
    for (int kt = 0; kt < E_DIM; kt += 32) {
        __syncthreads();   // drains tile-kt loads; also fences prior buf reads

        if (kt + 32 < E_DIM) {   // issue tile kt+32 into the other buffer
            const int nxt = cur ^ 1;
            load_lds16(Ag0 + kt + 32, As[nxt] + r0 * 32);
            load_lds16(Ag1 + kt + 32, As[nxt] + (64 + r0) * 32);
            load_lds16(Wg0 + kt + 32, Bs[nxt] + r0 * 32);
            load_lds16(Wg1 + kt + 32, Bs[nxt] + (64 + r0) * 32);
        }

        bf16x8 af[4], bfr[4];
#pragma unroll
        for (int i = 0; i < 4; i++)
            af[i] = *(const bf16x8*)(As[cur] + (wm + i * 16 + l16) * 32 + quad * 8);
#pragma unroll
        for (int j = 0; j < 4; j++)
            bfr[j] = *(const bf16x8*)(Bs[cur] + (wn + j * 16 + l16) * 32 + quad * 8);
#pragma unroll
        for (int i = 0; i < 4; i++)
#pragma unroll
            for (int j = 0; j < 4; j++)
                acc[i][j] = __builtin_amdgcn_mfma_f32_16x16x32_bf16(af[i], bfr[j], acc[i][j], 0, 0, 0);

        cur ^= 1;
    }

    // epilogue: C/D layout is col = lane&15, row = quad*4 + reg  [verified m89/m91]
#pragma unroll
    for (int j = 0; j < 4; j++) {
        const int n = bn + wn + j * 16 + l16;
        const float bv = bias[n];
#pragma unroll
        for (int i = 0; i < 4; i++) {
            const int m0 = bm + wm + i * 16 + quad * 4;
            if (mode == 3) {
#pragma unroll
                for (int r = 0; r < 4; r++)
                    outF[(size_t)(m0 + r) * E_DIM + n] = acc[i][j][r] + bv;
            } else if (mode == 2) {
                const int b_ = m0 >> 11, s0 = m0 & (S_LEN - 1);
                const int h = n >> 6, d = n & 63;
                bf16x4 pv;
#pragma unroll
                for (int r = 0; r < 4; r++) pv[r] = (bf16)(acc[i][j][r] + bv);
                *(bf16x4*)(outVt + ((size_t)((b_ * NH + h) * DH + d)) * S_LEN + s0) = pv;
            } else {
                bf16* o = (mode == 0) ? outQ : outK;
                const float sc = (mode == 0) ? 0.125f : 1.0f;
                const int h = n >> 6, d = n & 63;
#pragma unroll
                for (int r = 0; r < 4; r++) {
                    const int m = m0 + r;
                    const int b_ = m >> 11, s = m & (S_LEN - 1);
                    o[((size_t)(b_ * NH + h) * S_LEN + s) * DH + d] = (bf16)((acc[i][j][r] + bv) * sc);
                }
            }
        }
    }
}

// ---------------------------------------------------------------------------
// Flash attention, causal — R10 winner, verbatim: 128-row q-tile balanced
// pairs (p, 15-p) = 17 products/block, 256 blocks = 1/CU, hoisted shared
// LDS reads (each K/V fragment feeds both stripes), register prefetch of
// the next k-tile, unnormalized softmax. 85.2 us, no spill (VGPR 156).
// R11/R12 lesson: any build that targets >1 block/CU here spills (WRITE
// 130 MB) and eats the TLP gain — (256,1) is the only clean point.
// ---------------------------------------------------------------------------
__global__ __launch_bounds__(256, 1) void attn_kernel(
    const bf16* __restrict__ Qb, const bf16* __restrict__ Kb,
    const bf16* __restrict__ Vtb, bf16* __restrict__ Ob)
{
    __shared__ bf16 Ks[128 * 72];      // [kk][d]   18.0 KB
    __shared__ bf16 Vs[64 * 136];      // [d][kk]   17.0 KB
    __shared__ bf16 Ps[4][32 * 136];   // per-wave P, both stripes  34.0 KB

    const int t = threadIdx.x, lane = t & 63, w = t >> 6;
    const int quad = lane >> 4, l16 = lane & 15;

    const int i = blockIdx.x;
    const int xcd = i & 7, rr = i >> 3;        // rr: 0..31
    const int bh = (xcd << 2) | (rr & 3);
    const int pr = rr >> 2;                    // pair index 0..7
    const int qlo = pr, qhi = 15 - pr;         // the two 128-row q-tiles

    const bf16* Qg = Qb + (size_t)bh * S_LEN * DH;
    const bf16* Kg = Kb + (size_t)bh * S_LEN * DH;
    const bf16* Vg = Vtb + (size_t)bh * DH * S_LEN;
    const int b_ = bh >> 4, h = bh & 15;
    bf16* Og = Ob + (size_t)b_ * S_LEN * E_DIM + h * DH;

    bf16* Pw = Ps[w];
    const int inrow0 = w * 32;

    bf16x8 aq[2][2][2];
#pragma unroll
    for (int qt = 0; qt < 2; qt++) {
        const int qrow0 = (qt ? qhi : qlo) * 128 + inrow0;
#pragma unroll
        for (int st = 0; st < 2; st++) {
            const bf16* qp = Qg + (size_t)(qrow0 + st * 16 + l16) * DH + quad * 8;
            aq[qt][st][0] = *(const bf16x8*)(qp);
            aq[qt][st][1] = *(const bf16x8*)(qp + 32);
        }
    }

    f32x4 o[2][2][4];
    float l_part[2][2][4];
#pragma unroll
    for (int qt = 0; qt < 2; qt++)
#pragma unroll
        for (int st = 0; st < 2; st++)
#pragma unroll
            for (int dt = 0; dt < 4; dt++) {
                o[qt][st][dt] = f32x4{0.f, 0.f, 0.f, 0.f};
                l_part[qt][st][dt] = 0.f;
            }

    const int T = qhi + 1;
    const int krow = t >> 3, kcol8 = (t & 7) * 8;
    const int vrow = t >> 4, vcol8 = (t & 15) * 8;

    uint4 kc[4], vc[4];
#pragma unroll
    for (int k = 0; k < 4; k++)
        kc[k] = *(const uint4*)(Kg + (size_t)(krow + 32 * k) * DH + kcol8);
#pragma unroll
    for (int k = 0; k < 4; k++)
        vc[k] = *(const uint4*)(Vg + (size_t)(vrow + 16 * k) * S_LEN + vcol8);

    for (int kt = 0; kt < T; kt++) {
        __syncthreads();
#pragma unroll
        for (int k = 0; k < 4; k++)
            *(uint4*)(Ks + (krow + 32 * k) * 72 + kcol8) = kc[k];
#pragma unroll
        for (int k = 0; k < 4; k++)
            *(uint4*)(Vs + (vrow + 16 * k) * 136 + vcol8) = vc[k];
        __syncthreads();

        if (kt + 1 < T) {
            const int nb = (kt + 1) * 128;
#pragma unroll
            for (int k = 0; k < 4; k++)
                kc[k] = *(const uint4*)(Kg + (size_t)(nb + krow + 32 * k) * DH + kcol8);
#pragma unroll
            for (int k = 0; k < 4; k++)
                vc[k] = *(const uint4*)(Vg + (size_t)(vrow + 16 * k) * S_LEN + nb + vcol8);
        }

#pragma unroll
        for (int qt = 0; qt < 2; qt++) {
            if (qt == 0 && kt > qlo) continue;
            const bool diag = qt ? (kt == qhi) : (kt == qlo);

            f32x4 sv[2][8];
#pragma unroll
            for (int jt = 0; jt < 8; jt++) {
                const bf16* kp = Ks + (jt * 16 + l16) * 72 + quad * 8;
                bf16x8 bk0 = *(const bf16x8*)(kp);
                bf16x8 bk1 = *(const bf16x8*)(kp + 32);
#pragma unroll
                for (int st = 0; st < 2; st++) {
                    f32x4 s = f32x4{0.f, 0.f, 0.f, 0.f};
                    s = __builtin_amdgcn_mfma_f32_16x16x32_bf16(aq[qt][st][0], bk0, s, 0, 0, 0);
                    s = __builtin_amdgcn_mfma_f32_16x16x32_bf16(aq[qt][st][1], bk1, s, 0, 0, 0);
                    sv[st][jt] = s;
                }
            }

            if (diag) {
#pragma unroll
                for (int st = 0; st < 2; st++) {
                    const int inrow_base = inrow0 + st * 16 + quad * 4;
#pragma unroll
                    for (int jt = 0; jt < 8; jt++) {
                        const int kcol = jt * 16 + l16;
#pragma unroll
                        for (int r = 0; r < 4; r++)
                            if (kcol > inrow_base + r) sv[st][jt][r] = NEG_INF;
                    }
                }
            }

#pragma unroll
            for (int st = 0; st < 2; st++)
#pragma unroll
                for (int jt = 0; jt < 8; jt++)
#pragma unroll
                    for (int r = 0; r < 4; r++) {
                        const float pe = __expf(sv[st][jt][r]);
                        sv[st][jt][r] = pe;
                        l_part[qt][st][r] += pe;
                    }

#pragma unroll
            for (int st = 0; st < 2; st++)
#pragma unroll
                for (int jt = 0; jt < 8; jt++)
#pragma unroll
                    for (int r = 0; r < 4; r++)
                        Pw[(st * 16 + quad * 4 + r) * 136 + jt * 16 + l16] = (bf16)sv[st][jt][r];

#pragma unroll
            for (int ks = 0; ks < 4; ks++) {
                bf16x8 ap0 = *(const bf16x8*)(Pw + l16 * 136 + ks * 32 + quad * 8);
                bf16x8 ap1 = *(const bf16x8*)(Pw + (16 + l16) * 136 + ks * 32 + quad * 8);
#pragma unroll
                for (int dt = 0; dt < 4; dt++) {
                    bf16x8 bv = *(const bf16x8*)(Vs + (dt * 16 + l16) * 136 + ks * 32 + quad * 8);
                    o[qt][0][dt] = __builtin_amdgcn_mfma_f32_16x16x32_bf16(ap0, bv, o[qt][0][dt], 0, 0, 0);
                    o[qt][1][dt] = __builtin_amdgcn_mfma_f32_16x16x32_bf16(ap1, bv, o[qt][1][dt], 0, 0, 0);
                }
            }
        }
    }

#pragma unroll
    for (int qt = 0; qt < 2; qt++) {
        const int qrow0 = (qt ? qhi : qlo) * 128 + inrow0;
#pragma unroll
        for (int st = 0; st < 2; st++) {
#pragma unroll
            for (int r = 0; r < 4; r++) {
                float l = l_part[qt][st][r];
                l += __shfl_xor(l, 1);
                l += __shfl_xor(l, 2);
                l += __shfl_xor(l, 4);
                l += __shfl_xor(l, 8);
                l_part[qt][st][r] = 1.0f / l;
            }
#pragma unroll
            for (int r = 0; r < 4; r++) {
                const int srow = qrow0 + st * 16 + quad * 4 + r;
#pragma unroll
                for (int dt = 0; dt < 4; dt++)
                    Og[(size_t)srow * E_DIM + dt * 16 + l16] =
                        (bf16)(o[qt][st][dt][r] * l_part[qt][st][r]);
            }
        }
    }
}

// ---------------------------------------------------------------------------
extern "C" void kernel_launch(void* const* d_in, const int* in_sizes, int n_in,
                              void* d_out, int out_size, void* d_ws, size_t ws_size,
                              hipStream_t stream)
{
    const float* x  = (const float*)d_in[0];
    const float* Wq = (const float*)d_in[1];
    const float* bq = (const float*)d_in[2];
    const float* Wk = (const float*)d_in[3];
    const float* bk = (const float*)d_in[4];
    const float* Wv = (const float*)d_in[5];
    const float* bv = (const float*)d_in[6];
    const float* Wo = (const float*)d_in[7];
    const float* bo = (const float*)d_in[8];
    float* out = (float*)d_out;

    char* ws = (char*)d_ws;
    const size_t MB = 1ull << 20;
    bf16* xb  = (bf16*)(ws + 0);        //  8 MB: x   bf16 [4096][1024]
    bf16* wqb = (bf16*)(ws + 8 * MB);   //  2 MB
    bf16* wkb = (bf16*)(ws + 10 * MB);  //  2 MB
    bf16* wvb = (bf16*)(ws + 12 * MB);  //  2 MB
    bf16* wob = (bf16*)(ws + 14 * MB);  //  2 MB
    bf16* Qb  = (bf16*)(ws + 16 * MB);  //  8 MB: [b][h][s][d] (q pre-scaled by 1/8)
    bf16* Kb  = (bf16*)(ws + 24 * MB);  //  8 MB: [b][h][s][d]
    bf16* Vtb = (bf16*)(ws + 32 * MB);  //  8 MB: [b][h][d][s]
    bf16* Ab  = (bf16*)(ws + 40 * MB);  //  8 MB: attn out [b][s][e]

    // 1) fp32 -> bf16 for x and the four weight matrices
    convert_kernel<<<dim3(4096, 5), 256, 0, stream>>>(
        x, Wq, Wk, Wv, Wo, xb, wqb, wkb, wvb, wob, 4194304, 1048576);

    // 2) Q/K/V projections, single-barrier double-buffered staging
    gemm_kernel<<<dim3(8, 32, 3), 256, 0, stream>>>(
        xb, wqb, wkb, wvb, bq, bk, bv, Qb, Kb, Vtb, nullptr, 0);

    // 3) causal flash attention (R10 winner: balanced pairs, hoisted reads)
    attn_kernel<<<dim3(256), 256, 0, stream>>>(Qb, Kb, Vtb, Ab);

    // 4) output projection -> fp32 d_out
    gemm_kernel<<<dim3(8, 32, 1), 256, 0, stream>>>(
        Ab, wob, wob, wob, bo, bo, bo, nullptr, nullptr, nullptr, out, 1);
}

// Round 14
// 197.818 us; speedup vs baseline: 1.2230x; 1.1736x over previous
//
#include <hip/hip_runtime.h>
#include <stdint.h>

typedef __bf16 bf16;
typedef __bf16 bf16x8 __attribute__((ext_vector_type(8)));
typedef __bf16 bf16x4 __attribute__((ext_vector_type(4)));
typedef float  f32x4  __attribute__((ext_vector_type(4)));

#define E_DIM 1024
#define S_LEN 2048
#define BATCH 2
#define NH 16
#define DH 64

#define NEG_INF (-__builtin_inff())

// async global->LDS, 16B per lane; LDS dst = wave-uniform base + lane*16 (m104)
__device__ __forceinline__ void load_lds16(const bf16* g, bf16* l) {
    __builtin_amdgcn_global_load_lds(
        (const __attribute__((address_space(1))) void*)g,
        (__attribute__((address_space(3))) void*)l, 16, 0, 0);
}

// ---------------------------------------------------------------------------
// fp32 -> bf16 conversion for x, Wq, Wk, Wv, Wo
// ---------------------------------------------------------------------------
__global__ __launch_bounds__(256) void convert_kernel(
    const float* __restrict__ s0, const float* __restrict__ s1,
    const float* __restrict__ s2, const float* __restrict__ s3,
    const float* __restrict__ s4,
    bf16* __restrict__ d0, bf16* __restrict__ d1, bf16* __restrict__ d2,
    bf16* __restrict__ d3, bf16* __restrict__ d4,
    int n0, int n1)
{
    const float* src; bf16* dst; int n;
    switch (blockIdx.y) {
        case 0:  src = s0; dst = d0; n = n0; break;
        case 1:  src = s1; dst = d1; n = n1; break;
        case 2:  src = s2; dst = d2; n = n1; break;
        case 3:  src = s3; dst = d3; n = n1; break;
        default: src = s4; dst = d4; n = n1; break;
    }
    int i = (blockIdx.x * 256 + threadIdx.x) * 4;
    if (i >= n) return;
    float4 v = *(const float4*)(src + i);
    bf16x4 o;
    o[0] = (bf16)v.x; o[1] = (bf16)v.y; o[2] = (bf16)v.z; o[3] = (bf16)v.w;
    *(bf16x4*)(dst + i) = o;
}

// ---------------------------------------------------------------------------
// GEMM (R13, unchanged): m97 width-16 async staging + single-barrier double
// buffer, BK=32. C = A * W^T + bias.
// ---------------------------------------------------------------------------
__global__ __launch_bounds__(256) void gemm_kernel(
    const bf16* __restrict__ A,
    const bf16* __restrict__ W0, const bf16* __restrict__ W1, const bf16* __restrict__ W2,
    const float* __restrict__ bias0, const float* __restrict__ bias1, const float* __restrict__ bias2,
    bf16* __restrict__ outQ, bf16* __restrict__ outK, bf16* __restrict__ outVt,
    float* __restrict__ outF, int final_mode)
{
    __shared__ bf16 As[2][128 * 32];
    __shared__ bf16 Bs[2][128 * 32];

    int mode;
    const bf16* W; const float* bias;
    if (final_mode) { mode = 3; W = W0; bias = bias0; }
    else {
        mode = blockIdx.z;
        W    = (mode == 0) ? W0 : (mode == 1 ? W1 : W2);
        bias = (mode == 0) ? bias0 : (mode == 1 ? bias1 : bias2);
    }

    const int bm = blockIdx.y * 128, bn = blockIdx.x * 128;
    const int t = threadIdx.x;
    const int lane = t & 63, w = t >> 6;
    const int quad = lane >> 4, l16 = lane & 15;
    const int wm = (w & 1) * 64, wn = (w >> 1) * 64;

    const int r0 = w * 16;
    const int srow = r0 + (lane >> 2), scol = (lane & 3) * 8;
    const bf16* Ag0 = A + (size_t)(bm + srow) * E_DIM + scol;
    const bf16* Ag1 = Ag0 + (size_t)64 * E_DIM;
    const bf16* Wg0 = W + (size_t)(bn + srow) * E_DIM + scol;
    const bf16* Wg1 = Wg0 + (size_t)64 * E_DIM;

    f32x4 acc[4][4];
#pragma unroll
    for (int i = 0; i < 4; i++)
#pragma unroll
        for (int j = 0; j < 4; j++) acc[i][j] = f32x4{0.f, 0.f, 0.f, 0.f};

    load_lds16(Ag0, As[0] + r0 * 32);
    load_lds16(Ag1, As[0] + (64 + r0) * 32);
    load_lds16(Wg0, Bs[0] + r0 * 32);
    load_lds16(Wg1, Bs[0] + (64 + r0) * 32);

    int cur = 0;
    for (int kt = 0; kt < E_DIM; kt += 32) {
        __syncthreads();

        if (kt + 32 < E_DIM) {
            const int nxt = cur ^ 1;
            load_lds16(Ag0 + kt + 32, As[nxt] + r0 * 32);
            load_lds16(Ag1 + kt + 32, As[nxt] + (64 + r0) * 32);
            load_lds16(Wg0 + kt + 32, Bs[nxt] + r0 * 32);
            load_lds16(Wg1 + kt + 32, Bs[nxt] + (64 + r0) * 32);
        }

        bf16x8 af[4], bfr[4];
#pragma unroll
        for (int i = 0; i < 4; i++)
            af[i] = *(const bf16x8*)(As[cur] + (wm + i * 16 + l16) * 32 + quad * 8);
#pragma unroll
        for (int j = 0; j < 4; j++)
            bfr[j] = *(const bf16x8*)(Bs[cur] + (wn + j * 16 + l16) * 32 + quad * 8);
#pragma unroll
        for (int i = 0; i < 4; i++)
#pragma unroll
            for (int j = 0; j < 4; j++)
                acc[i][j] = __builtin_amdgcn_mfma_f32_16x16x32_bf16(af[i], bfr[j], acc[i][j], 0, 0, 0);

        cur ^= 1;
    }

#pragma unroll
    for (int j = 0; j < 4; j++) {
        const int n = bn + wn + j * 16 + l16;
        const float bv = bias[n];
#pragma unroll
        for (int i = 0; i < 4; i++) {
            const int m0 = bm + wm + i * 16 + quad * 4;
            if (mode == 3) {
#pragma unroll
                for (int r = 0; r < 4; r++)
                    outF[(size_t)(m0 + r) * E_DIM + n] = acc[i][j][r] + bv;
            } else if (mode == 2) {
                const int b_ = m0 >> 11, s0 = m0 & (S_LEN - 1);
                const int h = n >> 6, d = n & 63;
                bf16x4 pv;
#pragma unroll
                for (int r = 0; r < 4; r++) pv[r] = (bf16)(acc[i][j][r] + bv);
                *(bf16x4*)(outVt + ((size_t)((b_ * NH + h) * DH + d)) * S_LEN + s0) = pv;
            } else {
                bf16* o = (mode == 0) ? outQ : outK;
                const float sc = (mode == 0) ? 0.125f : 1.0f;
                const int h = n >> 6, d = n & 63;
#pragma unroll
                for (int r = 0; r < 4; r++) {
                    const int m = m0 + r;
                    const int b_ = m >> 11, s = m & (S_LEN - 1);
                    o[((size_t)(b_ * NH + h) * S_LEN + s) * DH + d] = (bf16)((acc[i][j][r] + bv) * sc);
                }
            }
        }
    }
}

// ---------------------------------------------------------------------------
// Flash attention, causal — 512-THREAD blocks (8 waves) for guaranteed TLP.
// R11/R12 lesson: at 256 threads the compiler spills to chase 4 waves/SIMD.
// A 512-block geometrically forces >=2 waves/SIMD, and this kernel is slim
// (~105 VGPRs: one 16-row stripe per q-tile per wave, per-jt streaming
// softmax, no register prefetch) so even the 128-reg 4-wave squeeze fits
// WITHOUT spill. Balanced pairs (p, 15-p) = 17 tile-products/block,
// 256 blocks; K/V staged once per 512 threads (half the per-wave staging
// of R13). LDS 69 KB -> up to 2 blocks/CU. Unnormalized softmax.
// ---------------------------------------------------------------------------
__global__ __launch_bounds__(512, 2) void attn_kernel(
    const bf16* __restrict__ Qb, const bf16* __restrict__ Kb,
    const bf16* __restrict__ Vtb, bf16* __restrict__ Ob)
{
    __shared__ bf16 Ks[128 * 72];      // [kk][d]   18.0 KB
    __shared__ bf16 Vs[64 * 136];      // [d][kk]   17.0 KB
    __shared__ bf16 Ps[8][16 * 136];   // per-wave P stripe  34.0 KB

    const int t = threadIdx.x, lane = t & 63, w = t >> 6;   // w: 0..7
    const int quad = lane >> 4, l16 = lane & 15;

    // 256 blocks: XCD gets 4 bh values (2 MB K/V -> L2-resident)
    const int i = blockIdx.x;
    const int xcd = i & 7, rr = i >> 3;        // rr: 0..31
    const int bh = (xcd << 2) | (rr & 3);
    const int pr = rr >> 2;                    // pair index 0..7
    const int qlo = pr, qhi = 15 - pr;         // the two 128-row q-tiles

    const bf16* Qg = Qb + (size_t)bh * S_LEN * DH;
    const bf16* Kg = Kb + (size_t)bh * S_LEN * DH;
    const bf16* Vg = Vtb + (size_t)bh * DH * S_LEN;
    const int b_ = bh >> 4, h = bh & 15;
    bf16* Og = Ob + (size_t)b_ * S_LEN * E_DIM + h * DH;

    bf16* Pw = Ps[w];
    const int inrow0 = w * 16;                 // wave's 16-row stripe in a q-tile

    // Q A-fragments: one stripe per q-tile (q pre-scaled by 1/8)
    bf16x8 aq[2][2];
#pragma unroll
    for (int qt = 0; qt < 2; qt++) {
        const int qrow0 = (qt ? qhi : qlo) * 128 + inrow0;
        const bf16* qp = Qg + (size_t)(qrow0 + l16) * DH + quad * 8;
        aq[qt][0] = *(const bf16x8*)(qp);
        aq[qt][1] = *(const bf16x8*)(qp + 32);
    }

    f32x4 o[2][4];
    float l_part[2][4];
#pragma unroll
    for (int qt = 0; qt < 2; qt++)
#pragma unroll
        for (int dt = 0; dt < 4; dt++) {
            o[qt][dt] = f32x4{0.f, 0.f, 0.f, 0.f};
            l_part[qt][dt] = 0.f;
        }

    const int T = qhi + 1;                     // staged k-tiles: 9..16
    // 512-thread staging maps (2 x 16B chunks each for K and V)
    const int kr0 = t >> 3, kce = (t & 7) * 8;     // K: rows kr0, kr0+64
    const int vr0 = t >> 4, vce = (t & 15) * 8;    // V: rows vr0, vr0+32

    for (int kt = 0; kt < T; kt++) {
        const int kb = kt * 128;
        uint4 k0 = *(const uint4*)(Kg + (size_t)(kb + kr0) * DH + kce);
        uint4 k1 = *(const uint4*)(Kg + (size_t)(kb + kr0 + 64) * DH + kce);
        uint4 v0 = *(const uint4*)(Vg + (size_t)vr0 * S_LEN + kb + vce);
        uint4 v1 = *(const uint4*)(Vg + (size_t)(vr0 + 32) * S_LEN + kb + vce);
        __syncthreads();   // previous tile's LDS reads done
        *(uint4*)(Ks + kr0 * 72 + kce) = k0;
        *(uint4*)(Ks + (kr0 + 64) * 72 + kce) = k1;
        *(uint4*)(Vs + vr0 * 136 + vce) = v0;
        *(uint4*)(Vs + (vr0 + 32) * 136 + vce) = v1;
        __syncthreads();   // staged tile visible

#pragma unroll
        for (int qt = 0; qt < 2; qt++) {
            if (qt == 0 && kt > qlo) continue;       // q_lo only needs tiles 0..qlo
            const bool diag = qt ? (kt == qhi) : (kt == qlo);
            const int irb = inrow0 + quad * 4;       // stripe row base (+r)

            // S = Q K^T -> mask -> exp -> P to LDS, streamed per 16-col chunk
#pragma unroll
            for (int jt = 0; jt < 8; jt++) {
                const bf16* kp = Ks + (jt * 16 + l16) * 72 + quad * 8;
                bf16x8 bk0 = *(const bf16x8*)(kp);
                bf16x8 bk1 = *(const bf16x8*)(kp + 32);
                f32x4 s = f32x4{0.f, 0.f, 0.f, 0.f};
                s = __builtin_amdgcn_mfma_f32_16x16x32_bf16(aq[qt][0], bk0, s, 0, 0, 0);
                s = __builtin_amdgcn_mfma_f32_16x16x32_bf16(aq[qt][1], bk1, s, 0, 0, 0);
                const int kcol = jt * 16 + l16;
#pragma unroll
                for (int r = 0; r < 4; r++) {
                    float sval = s[r];
                    if (diag && kcol > irb + r) sval = NEG_INF;
                    const float pe = __expf(sval);
                    l_part[qt][r] += pe;
                    Pw[(quad * 4 + r) * 136 + jt * 16 + l16] = (bf16)pe;
                }
            }

            // O += P V (V frags from LDS; P read back in A-layout)
#pragma unroll
            for (int ks = 0; ks < 4; ks++) {
                bf16x8 ap = *(const bf16x8*)(Pw + l16 * 136 + ks * 32 + quad * 8);
#pragma unroll
                for (int dt = 0; dt < 4; dt++) {
                    bf16x8 bv = *(const bf16x8*)(Vs + (dt * 16 + l16) * 136 + ks * 32 + quad * 8);
                    o[qt][dt] = __builtin_amdgcn_mfma_f32_16x16x32_bf16(ap, bv, o[qt][dt], 0, 0, 0);
                }
            }
        }
    }

    // epilogue: reduce row sums, normalize, write both q-tiles
#pragma unroll
    for (int qt = 0; qt < 2; qt++) {
        const int qrow0 = (qt ? qhi : qlo) * 128 + inrow0;
#pragma unroll
        for (int r = 0; r < 4; r++) {
            float l = l_part[qt][r];
            l += __shfl_xor(l, 1);
            l += __shfl_xor(l, 2);
            l += __shfl_xor(l, 4);
            l += __shfl_xor(l, 8);
            l_part[qt][r] = 1.0f / l;
        }
#pragma unroll
        for (int r = 0; r < 4; r++) {
            const int srow = qrow0 + quad * 4 + r;
#pragma unroll
            for (int dt = 0; dt < 4; dt++)
                Og[(size_t)srow * E_DIM + dt * 16 + l16] =
                    (bf16)(o[qt][dt][r] * l_part[qt][r]);
        }
    }
}

// ---------------------------------------------------------------------------
extern "C" void kernel_launch(void* const* d_in, const int* in_sizes, int n_in,
                              void* d_out, int out_size, void* d_ws, size_t ws_size,
                              hipStream_t stream)
{
    const float* x  = (const float*)d_in[0];
    const float* Wq = (const float*)d_in[1];
    const float* bq = (const float*)d_in[2];
    const float* Wk = (const float*)d_in[3];
    const float* bk = (const float*)d_in[4];
    const float* Wv = (const float*)d_in[5];
    const float* bv = (const float*)d_in[6];
    const float* Wo = (const float*)d_in[7];
    const float* bo = (const float*)d_in[8];
    float* out = (float*)d_out;

    char* ws = (char*)d_ws;
    const size_t MB = 1ull << 20;
    bf16* xb  = (bf16*)(ws + 0);        //  8 MB: x   bf16 [4096][1024]
    bf16* wqb = (bf16*)(ws + 8 * MB);   //  2 MB
    bf16* wkb = (bf16*)(ws + 10 * MB);  //  2 MB
    bf16* wvb = (bf16*)(ws + 12 * MB);  //  2 MB
    bf16* wob = (bf16*)(ws + 14 * MB);  //  2 MB
    bf16* Qb  = (bf16*)(ws + 16 * MB);  //  8 MB: [b][h][s][d] (q pre-scaled by 1/8)
    bf16* Kb  = (bf16*)(ws + 24 * MB);  //  8 MB: [b][h][s][d]
    bf16* Vtb = (bf16*)(ws + 32 * MB);  //  8 MB: [b][h][d][s]
    bf16* Ab  = (bf16*)(ws + 40 * MB);  //  8 MB: attn out [b][s][e]

    // 1) fp32 -> bf16 for x and the four weight matrices
    convert_kernel<<<dim3(4096, 5), 256, 0, stream>>>(
        x, Wq, Wk, Wv, Wo, xb, wqb, wkb, wvb, wob, 4194304, 1048576);

    // 2) Q/K/V projections, single-barrier double-buffered staging
    gemm_kernel<<<dim3(8, 32, 3), 256, 0, stream>>>(
        xb, wqb, wkb, wvb, bq, bk, bv, Qb, Kb, Vtb, nullptr, 0);

    // 3) causal flash attention (512-thread blocks, balanced pairs, slim regs)
    attn_kernel<<<dim3(256), 512, 0, stream>>>(Qb, Kb, Vtb, Ab);

    // 4) output projection -> fp32 d_out
    gemm_kernel<<<dim3(8, 32, 1), 256, 0, stream>>>(
        Ab, wob, wob, wob, bo, bo, bo, nullptr, nullptr, nullptr, out, 1);
}